// Round 1
// 229.557 us; speedup vs baseline: 1.0324x; 1.0324x over previous
//
#include <hip/hip_runtime.h>
#include <cstdint>

#define B_    4
#define S_    2048
#define D_    1024
#define SCALE 0.03125f     // 1/sqrt(1024)
#define NEG_BIG -1e9f

typedef __attribute__((ext_vector_type(8))) short short8;   // 8 bf16 (4 VGPRs)
typedef __attribute__((ext_vector_type(4))) float f32x4;    // MFMA C/D frag

__device__ __forceinline__ ushort f2bf(float f) {
  uint32_t u = __float_as_uint(f);
  u += 0x7fffu + ((u >> 16) & 1u);   // round-to-nearest-even
  return (ushort)(u >> 16);
}

__device__ __forceinline__ void load16_to_lds(const void* g, void* l) {
  __builtin_amdgcn_global_load_lds(
      (const __attribute__((address_space(1))) uint32_t*)g,
      (__attribute__((address_space(3))) uint32_t*)l, 16, 0, 0);
}

// ---------------- fused prep: convert Q, convert K, transpose+convert V -------
__global__ void prep(const float* __restrict__ Q, const float* __restrict__ K,
                     const float* __restrict__ V, ushort* __restrict__ Qb,
                     ushort* __restrict__ Kb, ushort* __restrict__ Vt) {
  __shared__ ushort tile[64][68];
  int id = blockIdx.x;
  if (id < 8192) {
    const float* X = (id < 4096) ? Q : K;
    ushort* Xb     = (id < 4096) ? Qb : Kb;
    int cid = id & 4095;
    size_t i = ((size_t)cid * 256 + threadIdx.x) * 8;
    float4 a = *(const float4*)(X + i);
    float4 c = *(const float4*)(X + i + 4);
    uint4 w;
    w.x = (uint)f2bf(a.x) | ((uint)f2bf(a.y) << 16);
    w.y = (uint)f2bf(a.z) | ((uint)f2bf(a.w) << 16);
    w.z = (uint)f2bf(c.x) | ((uint)f2bf(c.y) << 16);
    w.w = (uint)f2bf(c.z) | ((uint)f2bf(c.w) << 16);
    *(uint4*)(Xb + i) = w;
    return;
  }
  int t = id - 8192;                 // 0..2047
  int s0 = (t & 31) * 64, d0 = ((t >> 5) & 15) * 64, b = t >> 9;
  int tx = threadIdx.x & 15, ty = threadIdx.x >> 4;
  const float* src = V + ((size_t)b * S_ + s0) * D_ + d0;
  for (int i = 0; i < 4; ++i) {
    int row = ty + i * 16;
    float4 a = *(const float4*)(src + (size_t)row * D_ + tx * 4);
    ushort4 w;
    w.x = f2bf(a.x); w.y = f2bf(a.y); w.z = f2bf(a.z); w.w = f2bf(a.w);
    *(ushort4*)&tile[row][tx * 4] = w;
  }
  __syncthreads();
  ushort* dst = Vt + ((size_t)b * D_ + d0) * S_ + s0;
  for (int i = 0; i < 4; ++i) {
    int drow = ty + i * 16;
    ushort4 w;
    w.x = tile[tx * 4 + 0][drow];
    w.y = tile[tx * 4 + 1][drow];
    w.z = tile[tx * 4 + 2][drow];
    w.w = tile[tx * 4 + 3][drow];
    *(ushort4*)(dst + (size_t)drow * S_ + tx * 4) = w;
  }
}

// ---------------- ring-3 pipelined GEMM: C = A * Bt^T ------------------------
// BM=256, BN=128, BK=64. 512 threads = 8 waves (4M x 2N, 64x64 each).
// LDS: 3 slots x (A 32KB + B 16KB) = 144 KB ring. While slot t is read,
// slot t+1 is resident and slot t+2's 6 global_load_lds are in flight:
// steady-state wait is vmcnt(6) (counted, never 0) + raw s_barrier.
// T2 swizzle: byte ^= (row&7)<<4 via pre-swizzled global source (linear LDS
// dest for global_load_lds) + swizzled ds_read -> conflict-free b128 reads.
// EPI 0: C bf16 = f2bf(acc*SCALE + mask[col]*NEG_BIG).  EPI 1: C fp32 = acc.
template<int KDIM, int LDA, int LDB, int LDC,
         long long BATCHA, long long BATCHB, long long BATCHC,
         int NBN, int EPI, typename OutT>
__global__ __launch_bounds__(512, 2)
void gemm2(const ushort* __restrict__ A, const ushort* __restrict__ Bt,
           OutT* __restrict__ C, const int* __restrict__ mask) {
  constexpr int SLOT = (256 + 128) * 64;   // ushorts per ring slot (48 KB)
  constexpr int BOFF = 256 * 64;           // B region offset within slot
  constexpr int NT   = KDIM / 64;          // K-tiles
  __shared__ __align__(16) ushort lds[3 * SLOT];   // 144 KB

  // XCD-aware bijective chunked map (grid % 8 == 0), snake over bn per bm
  const int per = gridDim.x >> 3;
  int g = (blockIdx.x & 7) * per + (blockIdx.x >> 3);
  constexpr int TPB = 8 * NBN;             // tiles per batch (pow2)
  int b  = g / TPB;
  int t0 = g % TPB;
  int bm = t0 / NBN;
  int sn = t0 % NBN;
  int bn = (bm & 1) ? (NBN - 1 - sn) : sn;

  int tid  = threadIdx.x;
  int lane = tid & 63;
  int wave = tid >> 6;
  int wr = wave >> 1, wc = wave & 1;       // 4 x 2 wave grid
  int l16 = lane & 15, quad = lane >> 4;

  const ushort* Ab = A  + (size_t)b * BATCHA + (size_t)(bm * 256) * LDA;
  const ushort* Bb = Bt + (size_t)b * BATCHB + (size_t)(bn * 128) * LDB;

  // mask prefetch (QK only) before any staging so its vmem retires first
  float madd[4];
  if (EPI == 0) {
#pragma unroll
    for (int nt = 0; nt < 4; ++nt)
      madd[nt] = mask[b * S_ + bn * 128 + wc * 64 + nt * 16 + l16] ? NEG_BIG : 0.f;
  }

  f32x4 acc[4][4];
#pragma unroll
  for (int i = 0; i < 4; ++i)
#pragma unroll
    for (int j = 0; j < 4; ++j) acc[i][j] = (f32x4){0.f, 0.f, 0.f, 0.f};

  // stage K-tile kt into ring slot: 6 x global_load_lds (16B) per thread.
  // LDS dest linear; swizzle folded into global source (involution).
  auto stage = [&](int kt, int slot) {
#pragma unroll
    for (int j = 0; j < 4; ++j) {          // A: 256x64 = 2048 chunks
      int c = tid + j * 512;
      int row  = c >> 3;                   // 8 chunks per 128B row
      int col8 = (c & 7) * 8;              // ushort offset in row
      int src8 = col8 ^ ((row & 7) << 3);  // pre-swizzled source
      load16_to_lds(Ab + (size_t)row * LDA + (size_t)kt * 64 + src8,
                    lds + slot * SLOT + c * 8);
    }
#pragma unroll
    for (int j = 0; j < 2; ++j) {          // B: 128x64 = 1024 chunks
      int c = tid + j * 512;
      int row  = c >> 3;
      int col8 = (c & 7) * 8;
      int src8 = col8 ^ ((row & 7) << 3);
      load16_to_lds(Bb + (size_t)row * LDB + (size_t)kt * 64 + src8,
                    lds + slot * SLOT + BOFF + c * 8);
    }
  };

  // prologue: tiles 0,1 issued; wait own 6 oldest (tile 0) then barrier
  stage(0, 0);
  stage(1, 1);
  asm volatile("s_waitcnt vmcnt(6)\n"
               "s_barrier" ::: "memory");

  int sc = 0;
  for (int t = 0; t < NT; ++t) {
    int s2 = sc + 2; if (s2 >= 3) s2 -= 3;
    if (t + 2 < NT) stage(t + 2, s2);      // prefetch 2 tiles ahead

    const ushort* La = lds + sc * SLOT;
    const ushort* Lb = lds + sc * SLOT + BOFF;

    // ---- phase 0: mt 0..1, all B frags ----
    short8 a0[2][2], bfr[4][2];
#pragma unroll
    for (int ks = 0; ks < 2; ++ks) {
#pragma unroll
      for (int mt = 0; mt < 2; ++mt) {
        int row  = wr * 64 + mt * 16 + l16;
        int col8 = (ks * 32 + quad * 8) ^ ((row & 7) << 3);
        a0[mt][ks] = *(const short8*)(La + row * 64 + col8);
      }
#pragma unroll
      for (int nt = 0; nt < 4; ++nt) {
        int row  = wc * 64 + nt * 16 + l16;
        int col8 = (ks * 32 + quad * 8) ^ ((row & 7) << 3);
        bfr[nt][ks] = *(const short8*)(Lb + row * 64 + col8);
      }
    }
    __builtin_amdgcn_s_setprio(1);
#pragma unroll
    for (int ks = 0; ks < 2; ++ks)
#pragma unroll
      for (int mt = 0; mt < 2; ++mt)
#pragma unroll
        for (int nt = 0; nt < 4; ++nt)
          acc[mt][nt] = __builtin_amdgcn_mfma_f32_16x16x32_bf16(
              a0[mt][ks], bfr[nt][ks], acc[mt][nt], 0, 0, 0);
    __builtin_amdgcn_s_setprio(0);
    asm volatile("s_barrier" ::: "memory");

    // ---- phase 1: mt 2..3, reuse B frags ----
    short8 a1[2][2];
#pragma unroll
    for (int ks = 0; ks < 2; ++ks)
#pragma unroll
      for (int mt = 0; mt < 2; ++mt) {
        int row  = wr * 64 + (mt + 2) * 16 + l16;
        int col8 = (ks * 32 + quad * 8) ^ ((row & 7) << 3);
        a1[mt][ks] = *(const short8*)(La + row * 64 + col8);
      }
    __builtin_amdgcn_s_setprio(1);
#pragma unroll
    for (int ks = 0; ks < 2; ++ks)
#pragma unroll
      for (int mt = 0; mt < 2; ++mt)
#pragma unroll
        for (int nt = 0; nt < 4; ++nt)
          acc[mt + 2][nt] = __builtin_amdgcn_mfma_f32_16x16x32_bf16(
              a1[mt][ks], bfr[nt][ks], acc[mt + 2][nt], 0, 0, 0);
    __builtin_amdgcn_s_setprio(0);

    // counted wait: retire tile t+1 (next iter's reads), keep t+2 in flight
    if (t < NT - 3)
      asm volatile("s_waitcnt lgkmcnt(0)\n"
                   "s_waitcnt vmcnt(6)\n"
                   "s_barrier" ::: "memory");
    else
      asm volatile("s_waitcnt lgkmcnt(0)\n"
                   "s_waitcnt vmcnt(0)\n"
                   "s_barrier" ::: "memory");
    sc = (sc == 2) ? 0 : sc + 1;
  }

  // epilogue. C frag layout: col = lane&15, row = quad*4 + r
  OutT* Cb = C + (size_t)b * BATCHC + (size_t)(bm * 256) * LDC + (size_t)(bn * 128);
#pragma unroll
  for (int nt = 0; nt < 4; ++nt) {
    int col = wc * 64 + nt * 16 + l16;
#pragma unroll
    for (int mt = 0; mt < 4; ++mt)
#pragma unroll
      for (int r = 0; r < 4; ++r) {
        int row = wr * 64 + mt * 16 + quad * 4 + r;
        float v = acc[mt][nt][r];
        if (EPI == 0)
          Cb[(size_t)row * LDC + col] = (OutT)f2bf(v * SCALE + madd[nt]);
        else
          Cb[(size_t)row * LDC + col] = (OutT)v;
      }
  }
}

// ---------------- row softmax: S bf16 -> P bf16, one wave per row ------------
__global__ void softmax_rows(const ushort* __restrict__ S, ushort* __restrict__ P) {
  int row = blockIdx.x * 4 + (threadIdx.x >> 6);   // 0..8191 = b*2048+q
  int lane = threadIdx.x & 63;
  const ushort* src = S + (size_t)row * S_;

  float x[32];
#pragma unroll
  for (int j = 0; j < 4; ++j) {
    uint4 v = *(const uint4*)(src + lane * 8 + j * 512);
    uint32_t w[4] = {v.x, v.y, v.z, v.w};
#pragma unroll
    for (int t = 0; t < 4; ++t) {
      x[j * 8 + t * 2 + 0] = __uint_as_float(w[t] << 16);
      x[j * 8 + t * 2 + 1] = __uint_as_float(w[t] & 0xffff0000u);
    }
  }
  float m = x[0];
#pragma unroll
  for (int i = 1; i < 32; ++i) m = fmaxf(m, x[i]);
  for (int off = 1; off < 64; off <<= 1) m = fmaxf(m, __shfl_xor(m, off));

  float e[32], s = 0.f;
#pragma unroll
  for (int i = 0; i < 32; ++i) { e[i] = __expf(x[i] - m); s += e[i]; }
  for (int off = 1; off < 64; off <<= 1) s += __shfl_xor(s, off);
  float rinv = 1.0f / s;

  ushort* dst = P + (size_t)row * S_;
#pragma unroll
  for (int j = 0; j < 4; ++j) {
    uint4 w;
    uint32_t* pw = &w.x;
#pragma unroll
    for (int t = 0; t < 4; ++t)
      pw[t] = (uint32_t)f2bf(e[j * 8 + t * 2] * rinv) |
              ((uint32_t)f2bf(e[j * 8 + t * 2 + 1] * rinv) << 16);
    *(uint4*)(dst + lane * 8 + j * 512) = w;
  }
}

extern "C" void kernel_launch(void* const* d_in, const int* in_sizes, int n_in,
                              void* d_out, int out_size, void* d_ws, size_t ws_size,
                              hipStream_t stream) {
  const float* Q   = (const float*)d_in[0];
  const float* K   = (const float*)d_in[1];
  const float* V   = (const float*)d_in[2];
  const int*  mask = (const int*)d_in[3];
  float* Out = (float*)d_out;

  // ws: Qb(16.78M) Kb(16.78M) Vt(16.78M) Sb(bf16, 33.55M) = 83.9 MB.
  // P (bf16, 33.55M) aliases Qb+Kb (dead after QK GEMM).
  const size_t E = (size_t)B_ * S_ * D_;
  ushort* Qb = (ushort*)d_ws;
  ushort* Kb = Qb + E;
  ushort* Vt = Kb + E;
  ushort* Sb = Vt + E;
  ushort* P  = Qb;

  prep<<<10240, 256, 0, stream>>>(Q, K, V, Qb, Kb, Vt);

  // S[b][q][k] = bf16( SCALE * sum_d Qb[q][d] Kb[k][d] + mask[k]*NEG_BIG )
  gemm2<1024, 1024, 1024, 2048,
        (long long)2048 * 1024, (long long)2048 * 1024, (long long)2048 * 2048,
        16, 0, ushort>
      <<<512, 512, 0, stream>>>(Qb, Kb, Sb, mask);

  softmax_rows<<<2048, 256, 0, stream>>>(Sb, P);

  // Out[b][q][d] = sum_k P[q][k] Vt[d][k]
  gemm2<2048, 2048, 2048, 1024,
        (long long)2048 * 2048, (long long)1024 * 2048, (long long)2048 * 1024,
        8, 1, float>
      <<<256, 512, 0, stream>>>(P, Vt, Out, nullptr);
}

// Round 2
// 225.737 us; speedup vs baseline: 1.0498x; 1.0169x over previous
//
#include <hip/hip_runtime.h>
#include <cstdint>

#define B_    4
#define S_    2048
#define D_    1024
#define SCALE 0.03125f     // 1/sqrt(1024)
#define NEG_BIG -1e9f

typedef __attribute__((ext_vector_type(8))) short short8;   // 8 bf16 (4 VGPRs)
typedef __attribute__((ext_vector_type(4))) float f32x4;    // MFMA C/D frag

__device__ __forceinline__ ushort f2bf(float f) {
  uint32_t u = __float_as_uint(f);
  u += 0x7fffu + ((u >> 16) & 1u);   // round-to-nearest-even
  return (ushort)(u >> 16);
}

__device__ __forceinline__ void load16_to_lds(const void* g, void* l) {
  __builtin_amdgcn_global_load_lds(
      (const __attribute__((address_space(1))) uint32_t*)g,
      (__attribute__((address_space(3))) uint32_t*)l, 16, 0, 0);
}

#define BAR()   __builtin_amdgcn_s_barrier()
#define LGKM0() do { asm volatile("s_waitcnt lgkmcnt(0)" ::: "memory"); \
                     __builtin_amdgcn_sched_barrier(0); } while (0)
#define VM(n)   asm volatile("s_waitcnt vmcnt(" #n ")" ::: "memory")

// ---------------- fused prep: convert Q, convert K, transpose+convert V -------
__global__ void prep(const float* __restrict__ Q, const float* __restrict__ K,
                     const float* __restrict__ V, ushort* __restrict__ Qb,
                     ushort* __restrict__ Kb, ushort* __restrict__ Vt) {
  __shared__ ushort tile[64][68];
  int id = blockIdx.x;
  if (id < 8192) {
    const float* X = (id < 4096) ? Q : K;
    ushort* Xb     = (id < 4096) ? Qb : Kb;
    int cid = id & 4095;
    size_t i = ((size_t)cid * 256 + threadIdx.x) * 8;
    float4 a = *(const float4*)(X + i);
    float4 c = *(const float4*)(X + i + 4);
    uint4 w;
    w.x = (uint)f2bf(a.x) | ((uint)f2bf(a.y) << 16);
    w.y = (uint)f2bf(a.z) | ((uint)f2bf(a.w) << 16);
    w.z = (uint)f2bf(c.x) | ((uint)f2bf(c.y) << 16);
    w.w = (uint)f2bf(c.z) | ((uint)f2bf(c.w) << 16);
    *(uint4*)(Xb + i) = w;
    return;
  }
  int t = id - 8192;                 // 0..2047
  int s0 = (t & 31) * 64, d0 = ((t >> 5) & 15) * 64, b = t >> 9;
  int tx = threadIdx.x & 15, ty = threadIdx.x >> 4;
  const float* src = V + ((size_t)b * S_ + s0) * D_ + d0;
  for (int i = 0; i < 4; ++i) {
    int row = ty + i * 16;
    float4 a = *(const float4*)(src + (size_t)row * D_ + tx * 4);
    ushort4 w;
    w.x = f2bf(a.x); w.y = f2bf(a.y); w.z = f2bf(a.z); w.w = f2bf(a.w);
    *(ushort4*)&tile[row][tx * 4] = w;
  }
  __syncthreads();
  ushort* dst = Vt + ((size_t)b * D_ + d0) * S_ + s0;
  for (int i = 0; i < 4; ++i) {
    int drow = ty + i * 16;
    ushort4 w;
    w.x = tile[tx * 4 + 0][drow];
    w.y = tile[tx * 4 + 1][drow];
    w.z = tile[tx * 4 + 2][drow];
    w.w = tile[tx * 4 + 3][drow];
    *(ushort4*)(dst + (size_t)drow * S_ + tx * 4) = w;
  }
}

// ================= QK GEMM: 256x256 tile, BK=64, 8-phase (4/K-tile) ==========
// 8 waves (2M x 4N), per-wave 128x64 (mt0-7 x nt0-3). Dbuf LDS 128 KB.
// Per K-tile: 4 phases, each {stage 1 half-tile || ds_read subtile -> barrier
// -> lgkm0 -> setprio(1) 16 MFMA setprio(0) -> barrier}; vmcnt(4) per K-tile.
// Half issue order for tile T: A-lo @ blk(T-1)p0, A-hi @ p1 (other buffer),
// B-lo @ blk(T-2)p2, B-hi @ p3 (region freed after p1's B reads).
// Reads: p0: A-m0(8)+B-n0(4); p1: B-n1(4)+A-m1ks0(4); p2: A-m1ks1(4); p3: 0.
__global__ __launch_bounds__(512, 2)
void gemm_qk(const ushort* __restrict__ A, const ushort* __restrict__ Bt,
             ushort* __restrict__ C, const int* __restrict__ mask) {
  constexpr int NT  = 1024 / 64;        // 16 K-tiles
  constexpr int BUF = 512 * 64;         // ushorts per buffer (A 256x64 + B 256x64)
  constexpr int BO  = 256 * 64;         // B offset within buffer
  __shared__ __align__(16) ushort lds[2 * BUF];   // 128 KB -> 1 block/CU

  const int per = gridDim.x >> 3;       // XCD-bijective chunked map (grid%8==0)
  int g  = (blockIdx.x & 7) * per + (blockIdx.x >> 3);
  int b  = g >> 6;                      // 64 tiles per batch
  int t0 = g & 63;
  int bm = t0 >> 3;
  int sn = t0 & 7;
  int bn = (bm & 1) ? 7 - sn : sn;      // snake for L2 reuse of A panel

  int tid = threadIdx.x, lane = tid & 63, wave = tid >> 6;
  int wr = wave >> 2, wc = wave & 3;    // 2M x 4N wave grid
  int l16 = lane & 15, quad = lane >> 4;

  const ushort* Ab = A  + (size_t)b * (2048LL * 1024) + (size_t)(bm * 256) * 1024;
  const ushort* Bb = Bt + (size_t)b * (2048LL * 1024) + (size_t)(bn * 256) * 1024;

  // mask prefetch: issued first, so these vmem ops are oldest and retire at
  // the first counted vmcnt (accounting stays conservative).
  float madd[4];
#pragma unroll
  for (int nt = 0; nt < 4; ++nt)
    madd[nt] = mask[b * S_ + bn * 256 + wc * 64 + nt * 16 + l16] ? NEG_BIG : 0.f;

  f32x4 acc[8][4];
#pragma unroll
  for (int i = 0; i < 8; ++i)
#pragma unroll
    for (int j = 0; j < 4; ++j) acc[i][j] = (f32x4){0.f, 0.f, 0.f, 0.f};

  // stage half-tiles: linear LDS dest, T2 swizzle folded into global source.
  auto stageA = [&](int kt, int half) {
#pragma unroll
    for (int j = 0; j < 2; ++j) {
      int c = tid + j * 512;                    // 0..1023
      int row = half * 128 + (c >> 3);
      int col = ((c & 7) * 8) ^ ((row & 7) << 3);
      load16_to_lds(Ab + (size_t)row * 1024 + kt * 64 + col,
                    lds + (size_t)(kt & 1) * BUF + (half * 1024 + c) * 8);
    }
  };
  auto stageB = [&](int kt, int half) {
#pragma unroll
    for (int j = 0; j < 2; ++j) {
      int c = tid + j * 512;
      int row = half * 128 + (c >> 3);
      int col = ((c & 7) * 8) ^ ((row & 7) << 3);
      load16_to_lds(Bb + (size_t)row * 1024 + kt * 64 + col,
                    lds + (size_t)(kt & 1) * BUF + BO + (half * 1024 + c) * 8);
    }
  };

  // prologue: tile0 (4 halves) + tile1 B halves; vmcnt(4) -> tile0 resident,
  // B(1) in flight (steady-state entry).
  stageA(0, 0); stageA(0, 1); stageB(0, 0); stageB(0, 1);
  stageB(1, 0); stageB(1, 1);
  VM(4);
  BAR();

  for (int t = 0; t < NT; ++t) {
    const ushort* La = lds + (size_t)(t & 1) * BUF;
    const ushort* Lb = La + BO;
    short8 a0[4][2], a1[4][2], b0[2][2], b1[2][2];

    // ---- phase 0: MFMA (m0,n0) ----
    if (t + 1 < NT) stageA(t + 1, 0);
#pragma unroll
    for (int mt = 0; mt < 4; ++mt)
#pragma unroll
      for (int ks = 0; ks < 2; ++ks) {
        int row = wr * 128 + mt * 16 + l16;
        a0[mt][ks] = *(const short8*)(La + row * 64 + ((ks * 32 + quad * 8) ^ ((row & 7) << 3)));
      }
#pragma unroll
    for (int nt = 0; nt < 2; ++nt)
#pragma unroll
      for (int ks = 0; ks < 2; ++ks) {
        int row = wc * 64 + nt * 16 + l16;
        b0[nt][ks] = *(const short8*)(Lb + row * 64 + ((ks * 32 + quad * 8) ^ ((row & 7) << 3)));
      }
    BAR(); LGKM0();
    __builtin_amdgcn_s_setprio(1);
#pragma unroll
    for (int ks = 0; ks < 2; ++ks)
#pragma unroll
      for (int mt = 0; mt < 4; ++mt)
#pragma unroll
        for (int nt = 0; nt < 2; ++nt)
          acc[mt][nt] = __builtin_amdgcn_mfma_f32_16x16x32_bf16(
              a0[mt][ks], b0[nt][ks], acc[mt][nt], 0, 0, 0);
    __builtin_amdgcn_s_setprio(0);
    BAR();

    // ---- phase 1: MFMA (m0,n1) ----
    if (t + 1 < NT) stageA(t + 1, 1);
#pragma unroll
    for (int nt = 0; nt < 2; ++nt)
#pragma unroll
      for (int ks = 0; ks < 2; ++ks) {
        int row = wc * 64 + (nt + 2) * 16 + l16;
        b1[nt][ks] = *(const short8*)(Lb + row * 64 + ((ks * 32 + quad * 8) ^ ((row & 7) << 3)));
      }
#pragma unroll
    for (int mt = 0; mt < 4; ++mt) {
      int row = wr * 128 + (mt + 4) * 16 + l16;
      a1[mt][0] = *(const short8*)(La + row * 64 + ((quad * 8) ^ ((row & 7) << 3)));
    }
    BAR(); LGKM0();
    __builtin_amdgcn_s_setprio(1);
#pragma unroll
    for (int ks = 0; ks < 2; ++ks)
#pragma unroll
      for (int mt = 0; mt < 4; ++mt)
#pragma unroll
        for (int nt = 0; nt < 2; ++nt)
          acc[mt][nt + 2] = __builtin_amdgcn_mfma_f32_16x16x32_bf16(
              a0[mt][ks], b1[nt][ks], acc[mt][nt + 2], 0, 0, 0);
    __builtin_amdgcn_s_setprio(0);
    BAR();

    // ---- phase 2: MFMA (m1,n1); B region of this buffer now free ----
    if (t + 2 < NT) stageB(t + 2, 0);
#pragma unroll
    for (int mt = 0; mt < 4; ++mt) {
      int row = wr * 128 + (mt + 4) * 16 + l16;
      a1[mt][1] = *(const short8*)(La + row * 64 + ((32 + quad * 8) ^ ((row & 7) << 3)));
    }
    BAR(); LGKM0();
    __builtin_amdgcn_s_setprio(1);
#pragma unroll
    for (int ks = 0; ks < 2; ++ks)
#pragma unroll
      for (int mt = 0; mt < 4; ++mt)
#pragma unroll
        for (int nt = 0; nt < 2; ++nt)
          acc[mt + 4][nt + 2] = __builtin_amdgcn_mfma_f32_16x16x32_bf16(
              a1[mt][ks], b1[nt][ks], acc[mt + 4][nt + 2], 0, 0, 0);
    __builtin_amdgcn_s_setprio(0);
    BAR();

    // ---- phase 3: MFMA (m1,n0); A region also free ----
    if (t + 2 < NT) stageB(t + 2, 1);
    __builtin_amdgcn_s_setprio(1);
#pragma unroll
    for (int ks = 0; ks < 2; ++ks)
#pragma unroll
      for (int mt = 0; mt < 4; ++mt)
#pragma unroll
        for (int nt = 0; nt < 2; ++nt)
          acc[mt + 4][nt] = __builtin_amdgcn_mfma_f32_16x16x32_bf16(
              a1[mt][ks], b0[nt][ks], acc[mt + 4][nt], 0, 0, 0);
    __builtin_amdgcn_s_setprio(0);

    // counted wait once per K-tile: next tile's 4 halves retire, the 2 B
    // halves of tile t+2 stay in flight. Drain only at the tail.
    if (t < NT - 2)      VM(4);
    else if (t == NT - 2) VM(0);
    BAR();
  }

  // epilogue. C frag layout: col = lane&15, row = quad*4 + r
  ushort* Cb = C + (size_t)b * (2048LL * 2048) + (size_t)(bm * 256) * 2048 + bn * 256;
#pragma unroll
  for (int nt = 0; nt < 4; ++nt) {
    int col = wc * 64 + nt * 16 + l16;
#pragma unroll
    for (int mt = 0; mt < 8; ++mt)
#pragma unroll
      for (int r = 0; r < 4; ++r) {
        int row = wr * 128 + mt * 16 + quad * 4 + r;
        Cb[(size_t)row * 2048 + col] = f2bf(acc[mt][nt][r] * SCALE + madd[nt]);
      }
  }
}

// ================= PV GEMM: 256x128 tile, BK=64, 2 phases/K-tile =============
// 8 waves (4M x 2N), per-wave 64x64 (mt0-3 x nt0-3). Dbuf LDS 96 KB.
// Halves: A-lo/A-hi (2 loads each), B (2 loads). Issue: B(t+1)@p0 (other buf),
// A(t+2)@p1 (A region of current buf, freed after p0's A reads). vmcnt(4)/tile.
__global__ __launch_bounds__(512, 2)
void gemm_pv(const ushort* __restrict__ A, const ushort* __restrict__ Bt,
             float* __restrict__ C) {
  constexpr int NT  = 2048 / 64;        // 32 K-tiles
  constexpr int BUF = (256 + 128) * 64; // 24576 ushorts = 48 KB
  constexpr int BO  = 256 * 64;
  __shared__ __align__(16) ushort lds[2 * BUF];   // 96 KB

  const int per = gridDim.x >> 3;
  int g  = (blockIdx.x & 7) * per + (blockIdx.x >> 3);
  int b  = g >> 6;                      // 64 tiles per batch (8 bm x 8 bn)
  int t0 = g & 63;
  int bm = t0 >> 3;
  int sn = t0 & 7;
  int bn = (bm & 1) ? 7 - sn : sn;

  int tid = threadIdx.x, lane = tid & 63, wave = tid >> 6;
  int wr = wave >> 1, wc = wave & 1;    // 4M x 2N wave grid
  int l16 = lane & 15, quad = lane >> 4;

  const ushort* Ab = A  + (size_t)b * (2048LL * 2048) + (size_t)(bm * 256) * 2048;
  const ushort* Bb = Bt + (size_t)b * (1024LL * 2048) + (size_t)(bn * 128) * 2048;

  f32x4 acc[4][4];
#pragma unroll
  for (int i = 0; i < 4; ++i)
#pragma unroll
    for (int j = 0; j < 4; ++j) acc[i][j] = (f32x4){0.f, 0.f, 0.f, 0.f};

  auto stageA = [&](int kt, int half) {
#pragma unroll
    for (int j = 0; j < 2; ++j) {
      int c = tid + j * 512;
      int row = half * 128 + (c >> 3);
      int col = ((c & 7) * 8) ^ ((row & 7) << 3);
      load16_to_lds(Ab + (size_t)row * 2048 + kt * 64 + col,
                    lds + (size_t)(kt & 1) * BUF + (half * 1024 + c) * 8);
    }
  };
  auto stageB = [&](int kt) {
#pragma unroll
    for (int j = 0; j < 2; ++j) {
      int c = tid + j * 512;
      int row = c >> 3;                 // 0..127
      int col = ((c & 7) * 8) ^ ((row & 7) << 3);
      load16_to_lds(Bb + (size_t)row * 2048 + kt * 64 + col,
                    lds + (size_t)(kt & 1) * BUF + BO + c * 8);
    }
  };

  // prologue: tile0 + A(1); vmcnt(4) -> tile0 resident, A(1) in flight.
  stageA(0, 0); stageA(0, 1); stageB(0);
  stageA(1, 0); stageA(1, 1);
  VM(4);
  BAR();

  for (int t = 0; t < NT; ++t) {
    const ushort* La = lds + (size_t)(t & 1) * BUF;
    const ushort* Lb = La + BO;
    short8 a[4][2], b0[2][2], b1[2][2];

    // ---- phase 0: all A reads + B-n0; MFMA nt0-1 ----
    if (t + 1 < NT) stageB(t + 1);
#pragma unroll
    for (int mt = 0; mt < 4; ++mt)
#pragma unroll
      for (int ks = 0; ks < 2; ++ks) {
        int row = wr * 64 + mt * 16 + l16;
        a[mt][ks] = *(const short8*)(La + row * 64 + ((ks * 32 + quad * 8) ^ ((row & 7) << 3)));
      }
#pragma unroll
    for (int nt = 0; nt < 2; ++nt)
#pragma unroll
      for (int ks = 0; ks < 2; ++ks) {
        int row = wc * 64 + nt * 16 + l16;
        b0[nt][ks] = *(const short8*)(Lb + row * 64 + ((ks * 32 + quad * 8) ^ ((row & 7) << 3)));
      }
    BAR(); LGKM0();
    __builtin_amdgcn_s_setprio(1);
#pragma unroll
    for (int ks = 0; ks < 2; ++ks)
#pragma unroll
      for (int mt = 0; mt < 4; ++mt)
#pragma unroll
        for (int nt = 0; nt < 2; ++nt)
          acc[mt][nt] = __builtin_amdgcn_mfma_f32_16x16x32_bf16(
              a[mt][ks], b0[nt][ks], acc[mt][nt], 0, 0, 0);
    __builtin_amdgcn_s_setprio(0);
    BAR();

    // ---- phase 1: B-n1 reads; MFMA nt2-3; stage A(t+2) into freed A region --
    if (t + 2 < NT) { stageA(t + 2, 0); stageA(t + 2, 1); }
#pragma unroll
    for (int nt = 0; nt < 2; ++nt)
#pragma unroll
      for (int ks = 0; ks < 2; ++ks) {
        int row = wc * 64 + (nt + 2) * 16 + l16;
        b1[nt][ks] = *(const short8*)(Lb + row * 64 + ((ks * 32 + quad * 8) ^ ((row & 7) << 3)));
      }
    BAR(); LGKM0();
    __builtin_amdgcn_s_setprio(1);
#pragma unroll
    for (int ks = 0; ks < 2; ++ks)
#pragma unroll
      for (int mt = 0; mt < 4; ++mt)
#pragma unroll
        for (int nt = 0; nt < 2; ++nt)
          acc[mt][nt + 2] = __builtin_amdgcn_mfma_f32_16x16x32_bf16(
              a[mt][ks], b1[nt][ks], acc[mt][nt + 2], 0, 0, 0);
    __builtin_amdgcn_s_setprio(0);

    if (t < NT - 2)      VM(4);
    else if (t == NT - 2) VM(0);
    BAR();
  }

  float* Cb = C + (size_t)b * (2048LL * 1024) + (size_t)(bm * 256) * 1024 + bn * 128;
#pragma unroll
  for (int nt = 0; nt < 4; ++nt) {
    int col = wc * 64 + nt * 16 + l16;
#pragma unroll
    for (int mt = 0; mt < 4; ++mt)
#pragma unroll
      for (int r = 0; r < 4; ++r) {
        int row = wr * 64 + mt * 16 + quad * 4 + r;
        Cb[(size_t)row * 1024 + col] = acc[mt][nt][r];
      }
  }
}

// ---------------- row softmax: S bf16 -> P bf16, one wave per row ------------
__global__ void softmax_rows(const ushort* __restrict__ S, ushort* __restrict__ P) {
  int row = blockIdx.x * 4 + (threadIdx.x >> 6);   // 0..8191 = b*2048+q
  int lane = threadIdx.x & 63;
  const ushort* src = S + (size_t)row * S_;

  float x[32];
#pragma unroll
  for (int j = 0; j < 4; ++j) {
    uint4 v = *(const uint4*)(src + lane * 8 + j * 512);
    uint32_t w[4] = {v.x, v.y, v.z, v.w};
#pragma unroll
    for (int t = 0; t < 4; ++t) {
      x[j * 8 + t * 2 + 0] = __uint_as_float(w[t] << 16);
      x[j * 8 + t * 2 + 1] = __uint_as_float(w[t] & 0xffff0000u);
    }
  }
  float m = x[0];
#pragma unroll
  for (int i = 1; i < 32; ++i) m = fmaxf(m, x[i]);
  for (int off = 1; off < 64; off <<= 1) m = fmaxf(m, __shfl_xor(m, off));

  float e[32], s = 0.f;
#pragma unroll
  for (int i = 0; i < 32; ++i) { e[i] = __expf(x[i] - m); s += e[i]; }
  for (int off = 1; off < 64; off <<= 1) s += __shfl_xor(s, off);
  float rinv = 1.0f / s;

  ushort* dst = P + (size_t)row * S_;
#pragma unroll
  for (int j = 0; j < 4; ++j) {
    uint4 w;
    uint32_t* pw = &w.x;
#pragma unroll
    for (int t = 0; t < 4; ++t)
      pw[t] = (uint32_t)f2bf(e[j * 8 + t * 2] * rinv) |
              ((uint32_t)f2bf(e[j * 8 + t * 2 + 1] * rinv) << 16);
    *(uint4*)(dst + lane * 8 + j * 512) = w;
  }
}

extern "C" void kernel_launch(void* const* d_in, const int* in_sizes, int n_in,
                              void* d_out, int out_size, void* d_ws, size_t ws_size,
                              hipStream_t stream) {
  const float* Q   = (const float*)d_in[0];
  const float* K   = (const float*)d_in[1];
  const float* V   = (const float*)d_in[2];
  const int*  mask = (const int*)d_in[3];
  float* Out = (float*)d_out;

  // ws: Qb(16.78M) Kb(16.78M) Vt(16.78M) Sb(bf16, 33.55M) = 83.9 MB.
  // P (bf16, 33.55M) aliases Qb+Kb (dead after QK GEMM).
  const size_t E = (size_t)B_ * S_ * D_;
  ushort* Qb = (ushort*)d_ws;
  ushort* Kb = Qb + E;
  ushort* Vt = Kb + E;
  ushort* Sb = Vt + E;
  ushort* P  = Qb;

  prep<<<10240, 256, 0, stream>>>(Q, K, V, Qb, Kb, Vt);

  // S[b][q][k] = bf16( SCALE * sum_d Qb[q][d] Kb[k][d] + mask[k]*NEG_BIG )
  gemm_qk<<<256, 512, 0, stream>>>(Qb, Kb, Sb, mask);

  softmax_rows<<<2048, 256, 0, stream>>>(Sb, P);

  // Out[b][q][d] = sum_k P[q][k] Vt[d][k]
  gemm_pv<<<256, 512, 0, stream>>>(P, Vt, Out);
}